// Round 4
// baseline (1212.677 us; speedup 1.0000x reference)
//
#include <hip/hip_runtime.h>
#include <math.h>

#define Lc 4
#define Bc 4
#define Tc 1024
#define TCc 1024
#define T1c 2048
#define Dc 384
#define DKc 256
#define FFc 1536
#define TTc 0.1f
#define EPSc 1e-5f

typedef unsigned short u16;
typedef __attribute__((ext_vector_type(8))) __bf16 bf16x8;
typedef __attribute__((ext_vector_type(4))) float f32x4;

__device__ inline u16 f2bf(float f) {
  union { float f; unsigned u; } x; x.f = f;
  unsigned r = x.u + 0x7fffu + ((x.u >> 16) & 1u);
  return (u16)(r >> 16);
}

// ---------------- multi-tensor fp32 -> bf16 convert (float4/ushort4) ----------------
struct CDesc { const float* src; u16* dst; long n4; };
struct CPack { CDesc d[16]; long tot4; int nd; };

__global__ void cvt_multi(CPack P) {
  long i = (long)blockIdx.x * 256 + threadIdx.x;
  const long st = (long)gridDim.x * 256;
  for (; i < P.tot4; i += st) {
    long r = i; int g = 0;
    while (g < P.nd - 1 && r >= P.d[g].n4) { r -= P.d[g].n4; ++g; }
    float4 v = ((const float4*)P.d[g].src)[r];
    ushort4 o;
    o.x = f2bf(v.x); o.y = f2bf(v.y); o.z = f2bf(v.z); o.w = f2bf(v.w);
    ((ushort4*)P.d[g].dst)[r] = o;
  }
}

// concat per-layer biases: o[l*768+t] = t<384 ? a[l*384+t] : b[l*384+t-384]
__global__ void concat_bias(const float* __restrict__ a, const float* __restrict__ b,
                            float* __restrict__ o) {
  int l = blockIdx.x, t = threadIdx.x;
  o[l * 768 + t] = (t < Dc) ? a[l * Dc + t] : b[l * Dc + t - Dc];
}

// ------- score_c[z] (TC,T1) fp32 -> scT[z] (T1,TC) bf16, 64x64 tiles -------
__global__ __launch_bounds__(256) void transpose_cvt(const float* __restrict__ src,
                                                     u16* __restrict__ dst) {
  __shared__ float t[64 * 65];
  const int z = blockIdx.z;
  const float* s = src + (long)z * TCc * T1c;
  u16* d = dst + (long)z * T1c * TCc;
  const int s0 = blockIdx.x * 64, c0 = blockIdx.y * 64;
  const int tc = threadIdx.x >> 4;        // 0..15
  const int tx = (threadIdx.x & 15) * 4;  // 0,4,...,60
#pragma unroll
  for (int it = 0; it < 4; ++it) {
    const int c = tc + it * 16;
    float4 v = *(const float4*)(s + (long)(c0 + c) * T1c + s0 + tx);
    float* q = t + c * 65 + tx;
    q[0] = v.x; q[1] = v.y; q[2] = v.z; q[3] = v.w;
  }
  __syncthreads();
#pragma unroll
  for (int it = 0; it < 4; ++it) {
    const int srow = tc + it * 16;
    u16 o[4];
#pragma unroll
    for (int k2 = 0; k2 < 4; ++k2) o[k2] = f2bf(t[(tx + k2) * 65 + srow]);
    *(ushort4*)(d + (long)(s0 + srow) * TCc + c0 + tx) = *(ushort4*)o;
  }
}

// ---------------- unified bf16 GEMM: C = alpha*(A.B^T) + bias ----------------
// Runtime descriptors; up to 3 GEMMs per launch over a 1-D grid.
// out_mode: 0 f32 (split-K slab at kc*sSlab), 1 bf16, 2 f16.
// bias_mode: 0 none, 1 per-col, 2 per-row.  swiz: L2 swizzle for nbx=16,nby=8.
struct GDesc {
  const u16* A; const u16* B; void* C; const float* bias;
  float alpha; int N, K, lda, ldb;
  long sA, sB, sC, sBias, sSlab;
  int ksplit, bias_mode, relu, out_mode, swiz;
  int nbx, nby, cnt;   // cnt = nbx*nby*nbz
};
struct GPack { GDesc d[3]; int nd; };

__global__ __launch_bounds__(256) void gemm_u(GPack P) {
  __shared__ __attribute__((aligned(16))) u16 As[128 * 32];
  __shared__ __attribute__((aligned(16))) u16 Bs[128 * 32];
  int local = blockIdx.x;
  int gi = 0;
  while (gi < P.nd - 1 && local >= P.d[gi].cnt) { local -= P.d[gi].cnt; ++gi; }
  const GDesc D = P.d[gi];
  const int bx = local % D.nbx;
  const int rem = local / D.nbx;
  const int by = rem % D.nby;
  const int bz = rem / D.nby;
  const int b = bz / D.ksplit;
  const int kc = bz - b * D.ksplit;
  const int Klen = D.K / D.ksplit;
  const int k0 = kc * Klen;
  const u16* Ab = D.A + (long)b * D.sA;
  const u16* Bb = D.B + (long)b * D.sB;
  long tm, tn;
  if (D.swiz) {  // nbx=16, nby=8: co-resident blocks on one XCD share 2 n-tiles
    const int id = by * 16 + bx;
    tm = (long)(id >> 4) * 128;
    tn = (long)(2 * (id & 7) + ((id >> 3) & 1)) * 128;
  } else {
    tm = (long)by * 128; tn = (long)bx * 128;
  }
  const int tid = threadIdx.x;
  const int lane = tid & 63, wv = tid >> 6;
  const int wm = (wv >> 1) * 64, wn = (wv & 1) * 64;
  const int q = lane >> 4, r = lane & 15;
  const int ldr = lane >> 2;        // row within 16-row group
  const int ldc = (lane & 3) * 8;   // ushort offset within row (16B per lane)

  const f32x4 zero4 = {0.0f, 0.0f, 0.0f, 0.0f};
  f32x4 acc[4][4];
#pragma unroll
  for (int i = 0; i < 4; ++i)
#pragma unroll
    for (int j = 0; j < 4; ++j) acc[i][j] = zero4;

  for (int kt = k0; kt < k0 + Klen; kt += 32) {
#pragma unroll
    for (int j = 0; j < 2; ++j) {
      const int rowo = wv * 32 + j * 16;
      const u16* ga = Ab + (tm + rowo + ldr) * (long)D.lda + kt + ldc;
      __builtin_amdgcn_global_load_lds(
          (const __attribute__((address_space(1))) void*)ga,
          (__attribute__((address_space(3))) void*)(As + rowo * 32), 16, 0, 0);
      const u16* gb = Bb + (tn + rowo + ldr) * (long)D.ldb + kt + ldc;
      __builtin_amdgcn_global_load_lds(
          (const __attribute__((address_space(1))) void*)gb,
          (__attribute__((address_space(3))) void*)(Bs + rowo * 32), 16, 0, 0);
    }
    __syncthreads();

    bf16x8 af[4], bfr[4];
#pragma unroll
    for (int i = 0; i < 4; ++i) {
      af[i]  = *(const bf16x8*)(As + (wm + i * 16 + r) * 32 + q * 8);
      bfr[i] = *(const bf16x8*)(Bs + (wn + i * 16 + r) * 32 + q * 8);
    }
#pragma unroll
    for (int i = 0; i < 4; ++i)
#pragma unroll
      for (int j = 0; j < 4; ++j)
        acc[i][j] = __builtin_amdgcn_mfma_f32_16x16x32_bf16(af[i], bfr[j], acc[i][j], 0, 0, 0);
    __syncthreads();
  }

  // epilogue: D layout col=lane&15, row=(lane>>4)*4+reg  [measured m89/m91]
  const float* biasb = D.bias + (long)b * D.sBias;
#pragma unroll
  for (int i = 0; i < 4; ++i)
#pragma unroll
    for (int j = 0; j < 4; ++j)
#pragma unroll
      for (int v = 0; v < 4; ++v) {
        long row = tm + wm + i * 16 + q * 4 + v;
        long col = tn + wn + j * 16 + r;
        float val = acc[i][j][v] * D.alpha;
        if (D.bias_mode == 1 && kc == 0) val += biasb[col];
        if (D.bias_mode == 2 && kc == 0) val += biasb[row];
        if (D.relu) val = fmaxf(val, 0.0f);
        long idx = (long)kc * D.sSlab + (long)b * D.sC + row * (long)D.N + col;
        if (D.out_mode == 0)      ((float*)D.C)[idx] = val;
        else if (D.out_mode == 1) ((u16*)D.C)[idx] = f2bf(val);
        else                      ((_Float16*)D.C)[idx] = (_Float16)val;
      }
}

// -------- blended = TT*softmax(mixed) + (1-TT)*softmax(att), rows of T1 --------
__global__ __launch_bounds__(256) void blend_softmax(
    const _Float16* __restrict__ att, const _Float16* __restrict__ mixed,
    u16* __restrict__ out)
{
  const long row = blockIdx.x;
  const int tid = threadIdx.x;
  const _Float16* ar = att + row * T1c;
  const _Float16* mr = mixed + row * T1c;
  float a[8], m[8];
#pragma unroll
  for (int i = 0; i < 8; ++i) {
    a[i] = (float)ar[tid + i * 256];
    m[i] = (float)mr[tid + i * 256];
  }
  float amax = a[0], mmax = m[0];
#pragma unroll
  for (int i = 1; i < 8; ++i) { amax = fmaxf(amax, a[i]); mmax = fmaxf(mmax, m[i]); }
#pragma unroll
  for (int off = 32; off > 0; off >>= 1) {
    amax = fmaxf(amax, __shfl_xor(amax, off));
    mmax = fmaxf(mmax, __shfl_xor(mmax, off));
  }
  __shared__ float red[8];
  const int lane = tid & 63, wv = tid >> 6;
  if (lane == 0) { red[wv] = amax; red[4 + wv] = mmax; }
  __syncthreads();
  amax = fmaxf(fmaxf(red[0], red[1]), fmaxf(red[2], red[3]));
  mmax = fmaxf(fmaxf(red[4], red[5]), fmaxf(red[6], red[7]));
  __syncthreads();
  float asum = 0.f, msum = 0.f;
#pragma unroll
  for (int i = 0; i < 8; ++i) {
    a[i] = __expf(a[i] - amax); asum += a[i];
    m[i] = __expf(m[i] - mmax); msum += m[i];
  }
#pragma unroll
  for (int off = 32; off > 0; off >>= 1) {
    asum += __shfl_xor(asum, off);
    msum += __shfl_xor(msum, off);
  }
  if (lane == 0) { red[wv] = asum; red[4 + wv] = msum; }
  __syncthreads();
  asum = red[0] + red[1] + red[2] + red[3];
  msum = red[4] + red[5] + red[6] + red[7];
  const float ca = (1.0f - TTc) / asum, cm = TTc / msum;
#pragma unroll
  for (int i = 0; i < 8; ++i)
    out[row * T1c + tid + i * 256] = f2bf(a[i] * ca + m[i] * cm);
}

// -------- x = LN(xin + sum of 4 split-K slabs) ; writes fp32 x and bf16 x --------
__global__ __launch_bounds__(384) void add_ln4(
    const float* __restrict__ xin, const float* __restrict__ zs,
    const float* __restrict__ g, const float* __restrict__ be,
    float* __restrict__ xout, u16* __restrict__ xbf)
{
  const long row = blockIdx.x;
  const int d = threadIdx.x;
  const long SL = (long)Bc * Tc * Dc;
  const long o = row * Dc + d;
  float v = xin[o] + zs[o] + zs[SL + o] + zs[2 * SL + o] + zs[3 * SL + o];
  float s = v, s2 = v * v;
#pragma unroll
  for (int off = 32; off > 0; off >>= 1) {
    s  += __shfl_xor(s, off);
    s2 += __shfl_xor(s2, off);
  }
  __shared__ float red[12];
  const int lane = d & 63, wv = d >> 6;
  if (lane == 0) { red[wv] = s; red[6 + wv] = s2; }
  __syncthreads();
  float S = 0.f, S2 = 0.f;
#pragma unroll
  for (int w = 0; w < 6; ++w) { S += red[w]; S2 += red[6 + w]; }
  const float mean = S * (1.0f / Dc);
  const float var  = S2 * (1.0f / Dc) - mean * mean;
  const float rstd = rsqrtf(var + EPSc);
  const float y = (v - mean) * rstd * g[d] + be[d];
  xout[o] = y;
  xbf[o] = f2bf(y);
}

extern "C" void kernel_launch(void* const* d_in, const int* in_sizes, int n_in,
                              void* d_out, int out_size, void* d_ws, size_t ws_size,
                              hipStream_t stream)
{
  const float* tgt     = (const float*)d_in[0];
  const float* memory  = (const float*)d_in[1];
  const float* score_c = (const float*)d_in[2];
  const float* out_c   = (const float*)d_in[3];
  const float* Wq  = (const float*)d_in[4];  const float* bq  = (const float*)d_in[5];
  const float* Wk  = (const float*)d_in[6];  const float* bk  = (const float*)d_in[7];
  const float* Wv  = (const float*)d_in[8];  const float* bv  = (const float*)d_in[9];
  const float* Wkn = (const float*)d_in[10]; const float* bkn = (const float*)d_in[11];
  const float* Wun = (const float*)d_in[12]; const float* bun = (const float*)d_in[13];
  const float* W1  = (const float*)d_in[14]; const float* b1  = (const float*)d_in[15];
  const float* W2  = (const float*)d_in[16]; const float* b2  = (const float*)d_in[17];
  const float* g1  = (const float*)d_in[18]; const float* be1 = (const float*)d_in[19];
  const float* g2  = (const float*)d_in[20]; const float* be2 = (const float*)d_in[21];
  (void)in_sizes; (void)n_in; (void)out_size;

  char* p = (char*)d_ws;
  auto alloc = [&](size_t b) { char* r = p; p += (b + 255) & ~(size_t)255; return r; };

  u16* wk_bf   = (u16*)alloc((size_t)Lc * Dc * DKc * 2);
  u16* wv_bf   = (u16*)alloc((size_t)Lc * Dc * DKc * 2);
  u16* wkn_bf  = (u16*)alloc((size_t)Lc * Dc * Dc * 2);
  u16* w1_bf   = (u16*)alloc((size_t)Lc * FFc * Dc * 2);
  u16* w2_bf   = (u16*)alloc((size_t)Lc * Dc * FFc * 2);
  u16* wqu_bf  = (u16*)alloc((size_t)Lc * 2 * Dc * Dc * 2);  // [l][768][384]
  float* bqu   = (float*)alloc((size_t)Lc * 2 * Dc * 4);
  u16* mem_bf  = (u16*)alloc((size_t)Bc * T1c * DKc * 2);
  u16* outc_bf = (u16*)alloc((size_t)Lc * Bc * TCc * Dc * 2);
  u16* x_bf    = (u16*)alloc((size_t)Bc * Tc * Dc * 2);
  float* xbuf  = (float*)alloc((size_t)Bc * Tc * Dc * 4);
  u16* qunk_bf = (u16*)alloc((size_t)Bc * Tc * 2 * Dc * 2);   // [B*T][768]
  u16* k_all   = (u16*)alloc((size_t)Bc * T1c * Lc * Dc * 2); // [B*T1][1536]
  u16* vT_all  = (u16*)alloc((size_t)Bc * Lc * Dc * T1c * 2); // [b][1536][2048]
  u16* kno_all = (u16*)alloc((size_t)Lc * Bc * TCc * Dc * 2); // [l][B*TC][384]
  u16* s1_bf   = (u16*)alloc((size_t)Bc * Tc * TCc * 2);
  u16* scT_all = (u16*)alloc((size_t)Lc * Bc * T1c * TCc * 2);
  _Float16* att   = (_Float16*)alloc((size_t)Bc * Tc * T1c * 2);
  _Float16* mixed = (_Float16*)alloc((size_t)Bc * Tc * T1c * 2);
  u16* blended = (u16*)alloc((size_t)Bc * Tc * T1c * 2);
  float* zslab = (float*)alloc((size_t)4 * Bc * Tc * Dc * 4);
  float* yslab = (float*)alloc((size_t)4 * Bc * Tc * Dc * 4);
  u16* h_bf    = (u16*)alloc((size_t)Bc * Tc * FFc * 2);

  if ((size_t)(p - (char*)d_ws) > ws_size) return;  // fail loudly (poisoned out)

  // ---- single multi-convert launch (all fp32->bf16 tensors incl. wqu interleave) ----
  {
    CPack cp{}; int g = 0; long tot4 = 0;
    auto add = [&](const float* s, u16* d, long n) {
      cp.d[g].src = s; cp.d[g].dst = d; cp.d[g].n4 = n / 4; tot4 += n / 4; ++g;
    };
    add(Wk,  wk_bf,  (long)Lc * Dc * DKc);
    add(Wv,  wv_bf,  (long)Lc * Dc * DKc);
    add(Wkn, wkn_bf, (long)Lc * Dc * Dc);
    add(W1,  w1_bf,  (long)Lc * FFc * Dc);
    add(W2,  w2_bf,  (long)Lc * Dc * FFc);
    add(memory, mem_bf, (long)Bc * T1c * DKc);
    add(out_c, outc_bf, (long)Lc * Bc * TCc * Dc);
    add(tgt, x_bf, (long)Bc * Tc * Dc);
    for (int l = 0; l < Lc; ++l) {  // wqu = [Wq[l]; Wun[l]] rows
      add(Wq + (long)l * Dc * Dc,  wqu_bf + (long)l * 2 * Dc * Dc, (long)Dc * Dc);
      add(Wun + (long)l * Dc * Dc, wqu_bf + (long)l * 2 * Dc * Dc + Dc * Dc, (long)Dc * Dc);
    }
    cp.nd = g; cp.tot4 = tot4;
    cvt_multi<<<4096, 256, 0, stream>>>(cp);
  }
  concat_bias<<<Lc, 2 * Dc, 0, stream>>>(bq, bun, bqu);

  // scT_all: all L*B score_c panels transposed at once (64x64 tiles)
  transpose_cvt<<<dim3(T1c / 64, TCc / 64, Lc * Bc), 256, 0, stream>>>(score_c, scT_all);

  auto mkdesc = [](const u16* A, const u16* B, void* C, const float* bias,
                   float alpha, int N, int K, int lda, int ldb,
                   long sA, long sB, long sC, long sBias, long sSlab,
                   int ksplit, int bias_mode, int relu, int out_mode, int swiz,
                   int nbx, int nby, int nbz) {
    GDesc d; d.A = A; d.B = B; d.C = C; d.bias = bias; d.alpha = alpha;
    d.N = N; d.K = K; d.lda = lda; d.ldb = ldb;
    d.sA = sA; d.sB = sB; d.sC = sC; d.sBias = sBias; d.sSlab = sSlab;
    d.ksplit = ksplit; d.bias_mode = bias_mode; d.relu = relu;
    d.out_mode = out_mode; d.swiz = swiz;
    d.nbx = nbx; d.nby = nby; d.cnt = nbx * nby * nbz;
    return d;
  };
  auto launch = [&](GPack& pk) {
    int tot = 0;
    for (int i = 0; i < pk.nd; ++i) tot += pk.d[i].cnt;
    gemm_u<<<tot, 256, 0, stream>>>(pk);
  };

  const float scale = 1.0f / sqrtf((float)Dc);
  const long SLAB = (long)Bc * Tc * Dc;
  const float* nob = bqu;  // dummy non-null bias ptr for bias_mode=0

  // ---- pre-loop: k_all, vT_all, kno_all in ONE grouped launch ----
  {
    GPack pk{}; pk.nd = 3;
    // k_all = memory . Wk_allT + bk  (8192 x 1536, K=256)
    pk.d[0] = mkdesc(mem_bf, wk_bf, k_all, bk, 1.0f, Lc*Dc, DKc, DKc, DKc,
                     0, 0, 0, 0, 0, 1, 1, 0, 1, 0, Lc*Dc/128, Bc*T1c/128, 1);
    // vT_all[b] = Wv_all . memory[b]^T + bv(row)  (1536 x 2048, K=256) x B
    pk.d[1] = mkdesc(wv_bf, mem_bf, vT_all, bv, 1.0f, T1c, DKc, DKc, DKc,
                     0, (long)T1c*DKc, (long)Lc*Dc*T1c, 0, 0, 1, 2, 0, 1, 0,
                     T1c/128, Lc*Dc/128, Bc);
    // kno_all[l] = out_c[l] . Wkn[l]^T + bkn[l]  (4096 x 384, K=384) x L
    pk.d[2] = mkdesc(outc_bf, wkn_bf, kno_all, bkn, 1.0f, Dc, Dc, Dc, Dc,
                     (long)Bc*TCc*Dc, (long)Dc*Dc, (long)Bc*TCc*Dc, Dc, 0,
                     1, 1, 0, 1, 0, Dc/128, Bc*TCc/128, Lc);
    launch(pk);
  }

  for (int l = 0; l < Lc; ++l) {
    // qunk = x . [Wq;Wun]^T + [bq;bun]   (4096 x 768, K=384)
    {
      GPack pk{}; pk.nd = 1;
      pk.d[0] = mkdesc(x_bf, wqu_bf + (long)l*2*Dc*Dc, qunk_bf, bqu + l*2*Dc,
                       1.0f, 2*Dc, Dc, Dc, Dc, 0, 0, 0, 0, 0, 1, 1, 0, 1, 0,
                       2*Dc/128, Bc*Tc/128, 1);
      launch(pk);
    }
    // att (f16) + score1 (bf16) grouped — both depend only on qunk
    {
      GPack pk{}; pk.nd = 2;
      pk.d[0] = mkdesc(qunk_bf, k_all + l*Dc, att, nob, scale, T1c, Dc, 2*Dc, Lc*Dc,
                       (long)Tc*2*Dc, (long)T1c*Lc*Dc, (long)Tc*T1c, 0, 0,
                       1, 0, 0, 2, 0, T1c/128, Tc/128, Bc);
      pk.d[1] = mkdesc(qunk_bf + Dc, kno_all + (long)l*Bc*TCc*Dc, s1_bf, nob, scale,
                       TCc, Dc, 2*Dc, Dc, (long)Tc*2*Dc, (long)TCc*Dc, (long)Tc*TCc,
                       0, 0, 1, 0, 0, 1, 0, TCc/128, Tc/128, Bc);
      launch(pk);
    }
    // mixed[b] = score1[b] . scT[l][b]^T   (1024 x 2048, K=1024) -> f16, swizzled
    {
      GPack pk{}; pk.nd = 1;
      pk.d[0] = mkdesc(s1_bf, scT_all + (long)l*Bc*T1c*TCc, mixed, nob, 1.0f,
                       T1c, TCc, TCc, TCc, (long)Tc*TCc, (long)T1c*TCc, (long)Tc*T1c,
                       0, 0, 1, 0, 0, 2, 1, T1c/128, Tc/128, Bc);
      launch(pk);
    }
    // blended = TT*softmax(mixed) + (1-TT)*softmax(att)
    blend_softmax<<<Bc*Tc, 256, 0, stream>>>(att, mixed, blended);
    // z[b] = blended[b] . vT[l][b]^T   (1024 x 384, K=2048), split-K=4 slabs
    {
      GPack pk{}; pk.nd = 1;
      pk.d[0] = mkdesc(blended, vT_all + (long)l*Dc*T1c, zslab, nob, 1.0f,
                       Dc, T1c, T1c, T1c, (long)Tc*T1c, (long)Lc*Dc*T1c, (long)Tc*Dc,
                       0, SLAB, 4, 0, 0, 0, 0, Dc/128, Tc/128, Bc*4);
      launch(pk);
    }
    // x = LN(x + sum(zslab))
    add_ln4<<<Bc*Tc, Dc, 0, stream>>>(
        (l == 0) ? tgt : xbuf, zslab, g1 + l*Dc, be1 + l*Dc, xbuf, x_bf);
    // h = relu(x . W1^T + b1)   (4096 x 1536, K=384) bf16
    {
      GPack pk{}; pk.nd = 1;
      pk.d[0] = mkdesc(x_bf, w1_bf + (long)l*FFc*Dc, h_bf, b1 + l*FFc, 1.0f,
                       FFc, Dc, Dc, Dc, 0, 0, 0, 0, 0, 1, 1, 1, 1, 0,
                       FFc/128, Bc*Tc/128, 1);
      launch(pk);
    }
    // y2 = h . W2^T + b2   (4096 x 384, K=1536), split-K=4 slabs
    {
      GPack pk{}; pk.nd = 1;
      pk.d[0] = mkdesc(h_bf, w2_bf + (long)l*Dc*FFc, yslab, b2 + l*Dc, 1.0f,
                       Dc, FFc, FFc, FFc, 0, 0, 0, Dc, SLAB, 4, 1, 0, 0, 0,
                       Dc/128, Bc*Tc/128, 4);
      launch(pk);
    }
    // x = LN(x + sum(yslab)) ; last layer writes d_out
    add_ln4<<<Bc*Tc, Dc, 0, stream>>>(
        xbuf, yslab, g2 + l*Dc, be2 + l*Dc,
        (l == Lc - 1) ? (float*)d_out : xbuf, x_bf);
  }
}

// Round 5
// 1026.119 us; speedup vs baseline: 1.1818x; 1.1818x over previous
//
#include <hip/hip_runtime.h>
#include <math.h>

#define Lc 4
#define Bc 4
#define Tc 1024
#define TCc 1024
#define T1c 2048
#define Dc 384
#define DKc 256
#define FFc 1536
#define TTc 0.1f
#define EPSc 1e-5f

typedef unsigned short u16;
typedef __attribute__((ext_vector_type(8))) __bf16 bf16x8;
typedef __attribute__((ext_vector_type(4))) float f32x4;

__device__ inline u16 f2bf(float f) {
  union { float f; unsigned u; } x; x.f = f;
  unsigned r = x.u + 0x7fffu + ((x.u >> 16) & 1u);
  return (u16)(r >> 16);
}

// ---------------- multi-tensor fp32 -> bf16 convert (float4/ushort4) ----------------
struct CDesc { const float* src; u16* dst; long n4; };
struct CPack { CDesc d[16]; long tot4; int nd; };

__global__ void cvt_multi(CPack P) {
  long i = (long)blockIdx.x * 256 + threadIdx.x;
  const long st = (long)gridDim.x * 256;
  for (; i < P.tot4; i += st) {
    long r = i; int g = 0;
    while (g < P.nd - 1 && r >= P.d[g].n4) { r -= P.d[g].n4; ++g; }
    float4 v = ((const float4*)P.d[g].src)[r];
    ushort4 o;
    o.x = f2bf(v.x); o.y = f2bf(v.y); o.z = f2bf(v.z); o.w = f2bf(v.w);
    ((ushort4*)P.d[g].dst)[r] = o;
  }
}

// concat per-layer biases: o[l*768+t] = t<384 ? a[l*384+t] : b[l*384+t-384]
__global__ void concat_bias(const float* __restrict__ a, const float* __restrict__ b,
                            float* __restrict__ o) {
  int l = blockIdx.x, t = threadIdx.x;
  o[l * 768 + t] = (t < Dc) ? a[l * Dc + t] : b[l * Dc + t - Dc];
}

// ------- score_c[z] (TC,T1) fp32 -> scT[z] (T1,TC) bf16, 64x64 tiles -------
__global__ __launch_bounds__(256) void transpose_cvt(const float* __restrict__ src,
                                                     u16* __restrict__ dst) {
  __shared__ float t[64 * 65];
  const int z = blockIdx.z;
  const float* s = src + (long)z * TCc * T1c;
  u16* d = dst + (long)z * T1c * TCc;
  const int s0 = blockIdx.x * 64, c0 = blockIdx.y * 64;
  const int tc = threadIdx.x >> 4;        // 0..15
  const int tx = (threadIdx.x & 15) * 4;  // 0,4,...,60
#pragma unroll
  for (int it = 0; it < 4; ++it) {
    const int c = tc + it * 16;
    float4 v = *(const float4*)(s + (long)(c0 + c) * T1c + s0 + tx);
    float* q = t + c * 65 + tx;
    q[0] = v.x; q[1] = v.y; q[2] = v.z; q[3] = v.w;
  }
  __syncthreads();
#pragma unroll
  for (int it = 0; it < 4; ++it) {
    const int srow = tc + it * 16;
    u16 o[4];
#pragma unroll
    for (int k2 = 0; k2 < 4; ++k2) o[k2] = f2bf(t[(tx + k2) * 65 + srow]);
    *(ushort4*)(d + (long)(s0 + srow) * TCc + c0 + tx) = *(ushort4*)o;
  }
}

// ---------------- pipelined bf16 GEMM: C = alpha*(A.B^T) + bias ----------------
// A: (M,K) bf16 rows at stride lda, B: (N,K) bf16 rows at stride ldb.
// Grid: (N/128, M/128, batch*ksplit).  BIAS_MODE: 0 none, 1 per-col, 2 per-row.
// OUT_MODE: 0 f32 (split-K slab at kc*sSlab), 1 bf16, 2 f16.
// SWIZ: L2 swizzle for 16x8 grids.  K-loop is software-pipelined: register
// prefetch of tile k+1 overlaps MFMA of tile k (single LDS buffer).
template<int BIAS_MODE, int RELU, int OUT_MODE, int SWIZ>
__global__ __launch_bounds__(256) void gemm_bt(
    const u16* __restrict__ A, const u16* __restrict__ B,
    void* __restrict__ C, const float* __restrict__ bias,
    float alpha, int N, int K, int lda, int ldb,
    long sA, long sB, long sC, long sBias, int ksplit, long sSlab)
{
  __shared__ __attribute__((aligned(16))) u16 As[128 * 32];
  __shared__ __attribute__((aligned(16))) u16 Bs[128 * 32];
  const int bz = blockIdx.z;
  const int b = bz / ksplit;
  const int kc = bz - b * ksplit;
  const int Klen = K / ksplit;
  const int k0 = kc * Klen;
  const u16* Ab = A + (long)b * sA;
  const u16* Bb = B + (long)b * sB;
  long tm, tn;
  if (SWIZ) {  // grid (16,8,z): co-resident blocks on one XCD share 2 n-tiles
    const int id = blockIdx.y * 16 + blockIdx.x;
    tm = (long)(id >> 4) * 128;
    tn = (long)(2 * (id & 7) + ((id >> 3) & 1)) * 128;
  } else {
    tm = (long)blockIdx.y * 128; tn = (long)blockIdx.x * 128;
  }
  const int tid = threadIdx.x;
  const int lane = tid & 63, wv = tid >> 6;
  const int wm = (wv >> 1) * 64, wn = (wv & 1) * 64;
  const int q = lane >> 4, r = lane & 15;
  const int ldr = lane >> 2;        // row within 16-row group
  const int ldc = (lane & 3) * 8;   // u16 offset within row (16B per lane)

  // global srcs for this wave's staging chunks (2 x 16 rows for A and B)
  const u16* gA0 = Ab + (tm + wv * 32 + ldr) * (long)lda + k0 + ldc;
  const u16* gA1 = gA0 + 16 * (long)lda;
  const u16* gB0 = Bb + (tn + wv * 32 + ldr) * (long)ldb + k0 + ldc;
  const u16* gB1 = gB0 + 16 * (long)ldb;
  // LDS dsts (u16 index)
  u16* dA0 = As + (wv * 32 + ldr) * 32 + ldc;
  u16* dA1 = dA0 + 16 * 32;
  u16* dB0 = Bs + (wv * 32 + ldr) * 32 + ldc;
  u16* dB1 = dB0 + 16 * 32;

  const f32x4 zero4 = {0.0f, 0.0f, 0.0f, 0.0f};
  f32x4 acc[4][4];
#pragma unroll
  for (int i = 0; i < 4; ++i)
#pragma unroll
    for (int j = 0; j < 4; ++j) acc[i][j] = zero4;

  // prime tile 0
  uint4 ra0 = *(const uint4*)gA0;
  uint4 ra1 = *(const uint4*)gA1;
  uint4 rb0 = *(const uint4*)gB0;
  uint4 rb1 = *(const uint4*)gB1;

  const int iters = Klen >> 5;
  for (int it = 0; it < iters; ++it) {
    // all waves consumed previous tile (ds_reads forced lgkm wait via MFMA use)
    __builtin_amdgcn_s_barrier();
    *(uint4*)dA0 = ra0; *(uint4*)dA1 = ra1;
    *(uint4*)dB0 = rb0; *(uint4*)dB1 = rb1;
    __syncthreads();                 // lgkm drain + barrier; vmcnt already 0
    if (it + 1 < iters) {            // prefetch tile k+1 (overlaps MFMA below)
      const long o = (long)(it + 1) * 32;
      ra0 = *(const uint4*)(gA0 + o);
      ra1 = *(const uint4*)(gA1 + o);
      rb0 = *(const uint4*)(gB0 + o);
      rb1 = *(const uint4*)(gB1 + o);
    }
    bf16x8 af[4], bfr[4];
#pragma unroll
    for (int i = 0; i < 4; ++i) {
      af[i]  = *(const bf16x8*)(As + (wm + i * 16 + r) * 32 + q * 8);
      bfr[i] = *(const bf16x8*)(Bs + (wn + i * 16 + r) * 32 + q * 8);
    }
#pragma unroll
    for (int i = 0; i < 4; ++i)
#pragma unroll
      for (int j = 0; j < 4; ++j)
        acc[i][j] = __builtin_amdgcn_mfma_f32_16x16x32_bf16(af[i], bfr[j], acc[i][j], 0, 0, 0);
  }

  // epilogue: D layout col=lane&15, row=(lane>>4)*4+reg  [measured m89/m91]
  const float* biasb = bias ? bias + (long)b * sBias : nullptr;
#pragma unroll
  for (int i = 0; i < 4; ++i)
#pragma unroll
    for (int j = 0; j < 4; ++j)
#pragma unroll
      for (int v = 0; v < 4; ++v) {
        long row = tm + wm + i * 16 + q * 4 + v;
        long col = tn + wn + j * 16 + r;
        float val = acc[i][j][v] * alpha;
        if (BIAS_MODE == 1 && kc == 0) val += biasb[col];
        if (BIAS_MODE == 2 && kc == 0) val += biasb[row];
        if (RELU) val = fmaxf(val, 0.0f);
        long idx = (long)kc * sSlab + (long)b * sC + row * (long)N + col;
        if (OUT_MODE == 0)      ((float*)C)[idx] = val;
        else if (OUT_MODE == 1) ((u16*)C)[idx] = f2bf(val);
        else                    ((_Float16*)C)[idx] = (_Float16)val;
      }
}

// -------- blended = TT*softmax(mixed) + (1-TT)*softmax(att), rows of T1 --------
__global__ __launch_bounds__(256) void blend_softmax(
    const _Float16* __restrict__ att, const _Float16* __restrict__ mixed,
    u16* __restrict__ out)
{
  const long row = blockIdx.x;
  const int tid = threadIdx.x;
  const _Float16* ar = att + row * T1c;
  const _Float16* mr = mixed + row * T1c;
  float a[8], m[8];
#pragma unroll
  for (int i = 0; i < 8; ++i) {
    a[i] = (float)ar[tid + i * 256];
    m[i] = (float)mr[tid + i * 256];
  }
  float amax = a[0], mmax = m[0];
#pragma unroll
  for (int i = 1; i < 8; ++i) { amax = fmaxf(amax, a[i]); mmax = fmaxf(mmax, m[i]); }
#pragma unroll
  for (int off = 32; off > 0; off >>= 1) {
    amax = fmaxf(amax, __shfl_xor(amax, off));
    mmax = fmaxf(mmax, __shfl_xor(mmax, off));
  }
  __shared__ float red[8];
  const int lane = tid & 63, wv = tid >> 6;
  if (lane == 0) { red[wv] = amax; red[4 + wv] = mmax; }
  __syncthreads();
  amax = fmaxf(fmaxf(red[0], red[1]), fmaxf(red[2], red[3]));
  mmax = fmaxf(fmaxf(red[4], red[5]), fmaxf(red[6], red[7]));
  __syncthreads();
  float asum = 0.f, msum = 0.f;
#pragma unroll
  for (int i = 0; i < 8; ++i) {
    a[i] = __expf(a[i] - amax); asum += a[i];
    m[i] = __expf(m[i] - mmax); msum += m[i];
  }
#pragma unroll
  for (int off = 32; off > 0; off >>= 1) {
    asum += __shfl_xor(asum, off);
    msum += __shfl_xor(msum, off);
  }
  if (lane == 0) { red[wv] = asum; red[4 + wv] = msum; }
  __syncthreads();
  asum = red[0] + red[1] + red[2] + red[3];
  msum = red[4] + red[5] + red[6] + red[7];
  const float ca = (1.0f - TTc) / asum, cm = TTc / msum;
#pragma unroll
  for (int i = 0; i < 8; ++i)
    out[row * T1c + tid + i * 256] = f2bf(a[i] * ca + m[i] * cm);
}

// -------- x = LN(xin + sum of 4 split-K slabs) ; writes fp32 x and bf16 x --------
__global__ __launch_bounds__(384) void add_ln4(
    const float* __restrict__ xin, const float* __restrict__ zs,
    const float* __restrict__ g, const float* __restrict__ be,
    float* __restrict__ xout, u16* __restrict__ xbf)
{
  const long row = blockIdx.x;
  const int d = threadIdx.x;
  const long SL = (long)Bc * Tc * Dc;
  const long o = row * Dc + d;
  float v = xin[o] + zs[o] + zs[SL + o] + zs[2 * SL + o] + zs[3 * SL + o];
  float s = v, s2 = v * v;
#pragma unroll
  for (int off = 32; off > 0; off >>= 1) {
    s  += __shfl_xor(s, off);
    s2 += __shfl_xor(s2, off);
  }
  __shared__ float red[12];
  const int lane = d & 63, wv = d >> 6;
  if (lane == 0) { red[wv] = s; red[6 + wv] = s2; }
  __syncthreads();
  float S = 0.f, S2 = 0.f;
#pragma unroll
  for (int w = 0; w < 6; ++w) { S += red[w]; S2 += red[6 + w]; }
  const float mean = S * (1.0f / Dc);
  const float var  = S2 * (1.0f / Dc) - mean * mean;
  const float rstd = rsqrtf(var + EPSc);
  const float y = (v - mean) * rstd * g[d] + be[d];
  xout[o] = y;
  xbf[o] = f2bf(y);
}

extern "C" void kernel_launch(void* const* d_in, const int* in_sizes, int n_in,
                              void* d_out, int out_size, void* d_ws, size_t ws_size,
                              hipStream_t stream)
{
  const float* tgt     = (const float*)d_in[0];
  const float* memory  = (const float*)d_in[1];
  const float* score_c = (const float*)d_in[2];
  const float* out_c   = (const float*)d_in[3];
  const float* Wq  = (const float*)d_in[4];  const float* bq  = (const float*)d_in[5];
  const float* Wk  = (const float*)d_in[6];  const float* bk  = (const float*)d_in[7];
  const float* Wv  = (const float*)d_in[8];  const float* bv  = (const float*)d_in[9];
  const float* Wkn = (const float*)d_in[10]; const float* bkn = (const float*)d_in[11];
  const float* Wun = (const float*)d_in[12]; const float* bun = (const float*)d_in[13];
  const float* W1  = (const float*)d_in[14]; const float* b1  = (const float*)d_in[15];
  const float* W2  = (const float*)d_in[16]; const float* b2  = (const float*)d_in[17];
  const float* g1  = (const float*)d_in[18]; const float* be1 = (const float*)d_in[19];
  const float* g2  = (const float*)d_in[20]; const float* be2 = (const float*)d_in[21];
  (void)in_sizes; (void)n_in; (void)out_size;

  char* p = (char*)d_ws;
  auto alloc = [&](size_t b) { char* r = p; p += (b + 255) & ~(size_t)255; return r; };

  u16* wk_bf   = (u16*)alloc((size_t)Lc * Dc * DKc * 2);
  u16* wv_bf   = (u16*)alloc((size_t)Lc * Dc * DKc * 2);
  u16* wkn_bf  = (u16*)alloc((size_t)Lc * Dc * Dc * 2);
  u16* w1_bf   = (u16*)alloc((size_t)Lc * FFc * Dc * 2);
  u16* w2_bf   = (u16*)alloc((size_t)Lc * Dc * FFc * 2);
  u16* wqu_bf  = (u16*)alloc((size_t)Lc * 2 * Dc * Dc * 2);  // [l][768][384]
  float* bqu   = (float*)alloc((size_t)Lc * 2 * Dc * 4);
  u16* mem_bf  = (u16*)alloc((size_t)Bc * T1c * DKc * 2);
  u16* outc_bf = (u16*)alloc((size_t)Lc * Bc * TCc * Dc * 2);
  u16* x_bf    = (u16*)alloc((size_t)Bc * Tc * Dc * 2);
  float* xbuf  = (float*)alloc((size_t)Bc * Tc * Dc * 4);
  u16* qunk_bf = (u16*)alloc((size_t)Bc * Tc * 2 * Dc * 2);   // [B*T][768]
  u16* k_all   = (u16*)alloc((size_t)Bc * T1c * Lc * Dc * 2); // [B*T1][1536]
  u16* vT_all  = (u16*)alloc((size_t)Bc * Lc * Dc * T1c * 2); // [b][1536][2048]
  u16* kno_all = (u16*)alloc((size_t)Lc * Bc * TCc * Dc * 2); // [l][B*TC][384]
  u16* s1_bf   = (u16*)alloc((size_t)Bc * Tc * TCc * 2);
  u16* scT_all = (u16*)alloc((size_t)Lc * Bc * T1c * TCc * 2);
  _Float16* att   = (_Float16*)alloc((size_t)Bc * Tc * T1c * 2);
  _Float16* mixed = (_Float16*)alloc((size_t)Bc * Tc * T1c * 2);
  u16* blended = (u16*)alloc((size_t)Bc * Tc * T1c * 2);
  float* zslab = (float*)alloc((size_t)4 * Bc * Tc * Dc * 4);
  float* yslab = (float*)alloc((size_t)4 * Bc * Tc * Dc * 4);
  u16* h_bf    = (u16*)alloc((size_t)Bc * Tc * FFc * 2);

  if ((size_t)(p - (char*)d_ws) > ws_size) return;  // fail loudly (poisoned out)

  // ---- single multi-convert launch ----
  {
    CPack cp{}; int g = 0; long tot4 = 0;
    auto add = [&](const float* s, u16* d, long n) {
      cp.d[g].src = s; cp.d[g].dst = d; cp.d[g].n4 = n / 4; tot4 += n / 4; ++g;
    };
    add(Wk,  wk_bf,  (long)Lc * Dc * DKc);
    add(Wv,  wv_bf,  (long)Lc * Dc * DKc);
    add(Wkn, wkn_bf, (long)Lc * Dc * Dc);
    add(W1,  w1_bf,  (long)Lc * FFc * Dc);
    add(W2,  w2_bf,  (long)Lc * Dc * FFc);
    add(memory, mem_bf, (long)Bc * T1c * DKc);
    add(out_c, outc_bf, (long)Lc * Bc * TCc * Dc);
    add(tgt, x_bf, (long)Bc * Tc * Dc);
    for (int l = 0; l < Lc; ++l) {  // wqu = [Wq[l]; Wun[l]] rows
      add(Wq + (long)l * Dc * Dc,  wqu_bf + (long)l * 2 * Dc * Dc, (long)Dc * Dc);
      add(Wun + (long)l * Dc * Dc, wqu_bf + (long)l * 2 * Dc * Dc + Dc * Dc, (long)Dc * Dc);
    }
    cp.nd = g; cp.tot4 = tot4;
    cvt_multi<<<4096, 256, 0, stream>>>(cp);
  }
  concat_bias<<<Lc, 2 * Dc, 0, stream>>>(bq, bun, bqu);

  // scT_all: all L*B score_c panels transposed at once (64x64 tiles)
  transpose_cvt<<<dim3(T1c / 64, TCc / 64, Lc * Bc), 256, 0, stream>>>(score_c, scT_all);

  const float scale = 1.0f / sqrtf((float)Dc);
  const long SLAB = (long)Bc * Tc * Dc;

  // k_all = memory . Wk_allT + bk  (8192 x 1536, K=256)
  gemm_bt<1,0,1,0><<<dim3(Lc*Dc/128, Bc*T1c/128, 1), 256, 0, stream>>>(
      mem_bf, wk_bf, k_all, bk, 1.0f, Lc*Dc, DKc, DKc, DKc, 0, 0, 0, 0, 1, 0);
  // vT_all[b] = Wv_all . memory[b]^T + bv(row)  (1536 x 2048, K=256) x B
  gemm_bt<2,0,1,0><<<dim3(T1c/128, Lc*Dc/128, Bc), 256, 0, stream>>>(
      wv_bf, mem_bf, vT_all, bv, 1.0f, T1c, DKc, DKc, DKc,
      0, (long)T1c*DKc, (long)Lc*Dc*T1c, 0, 1, 0);
  // kno_all[l] = out_c[l] . Wkn[l]^T + bkn[l]  (4096 x 384, K=384) x L
  gemm_bt<1,0,1,0><<<dim3(Dc/128, Bc*TCc/128, Lc), 256, 0, stream>>>(
      outc_bf, wkn_bf, kno_all, bkn, 1.0f, Dc, Dc, Dc, Dc,
      (long)Bc*TCc*Dc, (long)Dc*Dc, (long)Bc*TCc*Dc, Dc, 1, 0);

  for (int l = 0; l < Lc; ++l) {
    // qunk = x . [Wq;Wun]^T + [bq;bun]   (4096 x 768, K=384)
    gemm_bt<1,0,1,0><<<dim3(2*Dc/128, Bc*Tc/128, 1), 256, 0, stream>>>(
        x_bf, wqu_bf + (long)l*2*Dc*Dc, qunk_bf, bqu + l*2*Dc,
        1.0f, 2*Dc, Dc, Dc, Dc, 0, 0, 0, 0, 1, 0);
    // att[b] = scale * q[b] . k[b]^T   (1024 x 2048, K=384) -> f16
    gemm_bt<0,0,2,0><<<dim3(T1c/128, Tc/128, Bc), 256, 0, stream>>>(
        qunk_bf, k_all + l*Dc, att, nullptr, scale, T1c, Dc, 2*Dc, Lc*Dc,
        (long)Tc*2*Dc, (long)T1c*Lc*Dc, (long)Tc*T1c, 0, 1, 0);
    // score1[b] = scale * unk[b] . kno[l][b]^T   (1024 x 1024, K=384) bf16
    gemm_bt<0,0,1,0><<<dim3(TCc/128, Tc/128, Bc), 256, 0, stream>>>(
        qunk_bf + Dc, kno_all + (long)l*Bc*TCc*Dc, s1_bf, nullptr, scale,
        TCc, Dc, 2*Dc, Dc, (long)Tc*2*Dc, (long)TCc*Dc, (long)Tc*TCc, 0, 1, 0);
    // mixed[b] = score1[b] . scT[l][b]^T   (1024 x 2048, K=1024) -> f16, swizzled
    gemm_bt<0,0,2,1><<<dim3(T1c/128, Tc/128, Bc), 256, 0, stream>>>(
        s1_bf, scT_all + (long)l*Bc*T1c*TCc, mixed, nullptr, 1.0f,
        T1c, TCc, TCc, TCc, (long)Tc*TCc, (long)T1c*TCc, (long)Tc*T1c, 0, 1, 0);
    // blended = TT*softmax(mixed) + (1-TT)*softmax(att)
    blend_softmax<<<Bc*Tc, 256, 0, stream>>>(att, mixed, blended);
    // z[b] = blended[b] . vT[l][b]^T   (1024 x 384, K=2048), split-K=4 slabs
    gemm_bt<0,0,0,0><<<dim3(Dc/128, Tc/128, Bc*4), 256, 0, stream>>>(
        blended, vT_all + (long)l*Dc*T1c, zslab, nullptr, 1.0f,
        Dc, T1c, T1c, T1c, (long)Tc*T1c, (long)Lc*Dc*T1c, (long)Tc*Dc, 0, 4, SLAB);
    // x = LN(x + sum(zslab))
    add_ln4<<<Bc*Tc, Dc, 0, stream>>>(
        (l == 0) ? tgt : xbuf, zslab, g1 + l*Dc, be1 + l*Dc, xbuf, x_bf);
    // h = relu(x . W1^T + b1)   (4096 x 1536, K=384) bf16
    gemm_bt<1,1,1,0><<<dim3(FFc/128, Bc*Tc/128, 1), 256, 0, stream>>>(
        x_bf, w1_bf + (long)l*FFc*Dc, h_bf, b1 + l*FFc, 1.0f,
        FFc, Dc, Dc, Dc, 0, 0, 0, 0, 1, 0);
    // y2 = h . W2^T + b2   (4096 x 384, K=1536), split-K=4 slabs
    gemm_bt<1,0,0,0><<<dim3(Dc/128, Bc*Tc/128, 4), 256, 0, stream>>>(
        h_bf, w2_bf + (long)l*Dc*FFc, yslab, b2 + l*Dc, 1.0f,
        Dc, FFc, FFc, FFc, 0, 0, 0, 0, 4, SLAB);
    // x = LN(x + sum(yslab)) ; last layer writes d_out
    add_ln4<<<Bc*Tc, Dc, 0, stream>>>(
        xbuf, yslab, g2 + l*Dc, be2 + l*Dc,
        (l == Lc - 1) ? (float*)d_out : xbuf, x_bf);
  }
}